// Round 1
// baseline (1166.045 us; speedup 1.0000x reference)
//
#include <hip/hip_runtime.h>
#include <hip/hip_bf16.h>

// GraphSAGE forward: 3 SAGEConv(mean, normalize=True) layers bracketed by linears.
// Strategy: build CSR (dst -> list of src) on device each launch, then
// wave-per-node fused kernels. f32 throughout (no fp32 MFMA on CDNA4; vector ALU).

#define NTHREADS 256

// ---------------- CSR build ----------------

__global__ void count_kernel(const int* __restrict__ dst, int* __restrict__ cnt, int m) {
    int e = blockIdx.x * blockDim.x + threadIdx.x;
    if (e < m) atomicAdd(&cnt[dst[e]], 1);
}

// single-block exclusive scan of cnt[0..n) -> row_ptr[0..n]
__global__ void scan_kernel(const int* __restrict__ cnt, int* __restrict__ row_ptr, int n) {
    __shared__ int wsum[16];
    __shared__ int s_total;
    __shared__ int s_carry;
    const int tid = threadIdx.x;
    const int lane = tid & 63;
    const int wid = tid >> 6;
    if (tid == 0) s_carry = 0;
    __syncthreads();
    for (int base = 0; base < n; base += 1024) {
        const int i = base + tid;
        int v = (i < n) ? cnt[i] : 0;
        int x = v;
        #pragma unroll
        for (int off = 1; off < 64; off <<= 1) {
            int t = __shfl_up(x, off, 64);
            if (lane >= off) x += t;
        }
        if (lane == 63) wsum[wid] = x;
        __syncthreads();
        if (wid == 0) {
            int wv = (lane < 16) ? wsum[lane] : 0;
            int wx = wv;
            #pragma unroll
            for (int off = 1; off < 16; off <<= 1) {
                int t = __shfl_up(wx, off, 64);
                if (lane >= off) wx += t;
            }
            if (lane == 15) s_total = wx;          // chunk total
            if (lane < 16) wsum[lane] = wx - wv;   // exclusive wave offsets
        }
        __syncthreads();
        const int wave_excl = wsum[wid];
        const int carry = s_carry;
        if (i < n) row_ptr[i] = carry + wave_excl + (x - v);
        __syncthreads();
        if (tid == 0) s_carry = carry + s_total;
        __syncthreads();
    }
    if (tid == 0) row_ptr[n] = s_carry;
}

__global__ void fill_kernel(const int* __restrict__ src, const int* __restrict__ dst,
                            const int* __restrict__ row_ptr, int* __restrict__ cursor,
                            int* __restrict__ csr_src, int m) {
    int e = blockIdx.x * blockDim.x + threadIdx.x;
    if (e < m) {
        int d = dst[e];
        int pos = row_ptr[d] + atomicAdd(&cursor[d], 1);
        csr_src[pos] = src[e];
    }
}

__global__ void invdeg_kernel(const int* __restrict__ row_ptr, float* __restrict__ inv_deg, int n) {
    int i = blockIdx.x * blockDim.x + threadIdx.x;
    if (i < n) {
        int d = row_ptr[i + 1] - row_ptr[i];
        inv_deg[i] = (d > 0) ? 1.0f / (float)d : 0.0f;
    }
}

// ---------------- dense layers ----------------

// h[n,64] = x[n,128] @ W1[128,64] + b1
__global__ __launch_bounds__(NTHREADS) void linear1_kernel(
    const float* __restrict__ x, const float* __restrict__ W1,
    const float* __restrict__ b1, float* __restrict__ h, int n) {
    __shared__ float Ws[128 * 64];   // 32 KB
    for (int idx = threadIdx.x; idx < 128 * 64; idx += NTHREADS) Ws[idx] = W1[idx];
    __syncthreads();
    const int lane = threadIdx.x & 63;
    const int wid  = threadIdx.x >> 6;
    const float bj = b1[lane];
    const int waves_total = gridDim.x * (NTHREADS / 64);
    for (int node = blockIdx.x * (NTHREADS / 64) + wid; node < n; node += waves_total) {
        const float x0 = x[node * 128 + lane];
        const float x1 = x[node * 128 + 64 + lane];
        float o = bj;
        #pragma unroll
        for (int k = 0; k < 64; ++k)
            o += __shfl(x0, k, 64) * Ws[k * 64 + lane];
        #pragma unroll
        for (int k = 0; k < 64; ++k)
            o += __shfl(x1, k, 64) * Ws[(64 + k) * 64 + lane];
        h[node * 64 + lane] = o;
    }
}

// one SAGE layer: agg = mean of hin[src]; o = agg@Wl + bl + hin@Wr; L2-norm; relu
__global__ __launch_bounds__(NTHREADS) void sage_layer_kernel(
    const float* __restrict__ hin, const int* __restrict__ row_ptr,
    const int* __restrict__ csr_src, const float* __restrict__ inv_deg,
    const float* __restrict__ Wl, const float* __restrict__ bl,
    const float* __restrict__ Wr, float* __restrict__ hout, int n) {
    __shared__ float Wls[64 * 64];   // 16 KB
    __shared__ float Wrs[64 * 64];   // 16 KB
    for (int idx = threadIdx.x; idx < 64 * 64; idx += NTHREADS) {
        Wls[idx] = Wl[idx];
        Wrs[idx] = Wr[idx];
    }
    __syncthreads();
    const int lane = threadIdx.x & 63;
    const int wid  = threadIdx.x >> 6;
    const float bj = bl[lane];
    const int waves_total = gridDim.x * (NTHREADS / 64);
    for (int node = blockIdx.x * (NTHREADS / 64) + wid; node < n; node += waves_total) {
        const int rs = row_ptr[node];
        const int re = row_ptr[node + 1];
        float acc = 0.0f;
        int e = rs;
        for (; e + 4 <= re; e += 4) {
            const int s0 = csr_src[e];
            const int s1 = csr_src[e + 1];
            const int s2 = csr_src[e + 2];
            const int s3 = csr_src[e + 3];
            float a0 = hin[s0 * 64 + lane];
            float a1 = hin[s1 * 64 + lane];
            float a2 = hin[s2 * 64 + lane];
            float a3 = hin[s3 * 64 + lane];
            acc += a0 + a1 + a2 + a3;
        }
        for (; e < re; ++e) acc += hin[csr_src[e] * 64 + lane];
        const float agg = acc * inv_deg[node];
        const float hv  = hin[node * 64 + lane];
        float o = bj;
        #pragma unroll
        for (int k = 0; k < 64; ++k) {
            o += __shfl(agg, k, 64) * Wls[k * 64 + lane];
            o += __shfl(hv,  k, 64) * Wrs[k * 64 + lane];
        }
        // row L2 norm across 64 lanes
        float ss = o * o;
        #pragma unroll
        for (int off = 32; off > 0; off >>= 1) ss += __shfl_xor(ss, off, 64);
        const float norm = sqrtf(ss);
        float v = o / fmaxf(norm, 1e-12f);
        hout[node * 64 + lane] = fmaxf(v, 0.0f);
    }
}

// out[n,64] = h[n,64] @ W2[64,64] + b2
__global__ __launch_bounds__(NTHREADS) void linear2_kernel(
    const float* __restrict__ h, const float* __restrict__ W2,
    const float* __restrict__ b2, float* __restrict__ out, int n) {
    __shared__ float Ws[64 * 64];
    for (int idx = threadIdx.x; idx < 64 * 64; idx += NTHREADS) Ws[idx] = W2[idx];
    __syncthreads();
    const int lane = threadIdx.x & 63;
    const int wid  = threadIdx.x >> 6;
    const float bj = b2[lane];
    const int waves_total = gridDim.x * (NTHREADS / 64);
    for (int node = blockIdx.x * (NTHREADS / 64) + wid; node < n; node += waves_total) {
        const float hv = h[node * 64 + lane];
        float o = bj;
        #pragma unroll
        for (int k = 0; k < 64; ++k)
            o += __shfl(hv, k, 64) * Ws[k * 64 + lane];
        out[node * 64 + lane] = o;
    }
}

// ---------------- launch ----------------

extern "C" void kernel_launch(void* const* d_in, const int* in_sizes, int n_in,
                              void* d_out, int out_size, void* d_ws, size_t ws_size,
                              hipStream_t stream) {
    const float* x  = (const float*)d_in[0];
    const int*   ei = (const int*)  d_in[1];
    const float* W1 = (const float*)d_in[2];
    const float* b1 = (const float*)d_in[3];
    const float* Wl = (const float*)d_in[4];
    const float* bl = (const float*)d_in[5];
    const float* Wr = (const float*)d_in[6];
    const float* W2 = (const float*)d_in[7];
    const float* b2 = (const float*)d_in[8];
    float* out = (float*)d_out;

    const int n = in_sizes[0] / 128;   // 100000
    const int m = in_sizes[1] / 2;     // 1250000
    const int* src = ei;
    const int* dst = ei + m;

    char* ws = (char*)d_ws;
    size_t off = 0;
    auto alloc = [&](size_t bytes) -> void* {
        void* p = ws + off;
        off = (off + bytes + 255) & ~(size_t)255;
        return p;
    };
    float* hA      = (float*)alloc((size_t)n * 64 * sizeof(float));
    float* hB      = (float*)alloc((size_t)n * 64 * sizeof(float));
    float* inv_deg = (float*)alloc((size_t)n * sizeof(float));
    int*   row_ptr = (int*)  alloc((size_t)(n + 1) * sizeof(int));
    int*   cnt     = (int*)  alloc((size_t)n * sizeof(int));
    int*   cursor  = (int*)  alloc((size_t)n * sizeof(int));
    int*   csr     = (int*)  alloc((size_t)m * sizeof(int));

    hipMemsetAsync(cnt, 0, (size_t)n * sizeof(int), stream);
    hipMemsetAsync(cursor, 0, (size_t)n * sizeof(int), stream);

    const int eb = (m + NTHREADS - 1) / NTHREADS;
    const int nb = (n + NTHREADS - 1) / NTHREADS;
    count_kernel<<<eb, NTHREADS, 0, stream>>>(dst, cnt, m);
    scan_kernel<<<1, 1024, 0, stream>>>(cnt, row_ptr, n);
    fill_kernel<<<eb, NTHREADS, 0, stream>>>(src, dst, row_ptr, cursor, csr, m);
    invdeg_kernel<<<nb, NTHREADS, 0, stream>>>(row_ptr, inv_deg, n);

    linear1_kernel<<<2048, NTHREADS, 0, stream>>>(x, W1, b1, hA, n);

    const float* hi = hA;
    float* ho = hB;
    for (int i = 0; i < 3; ++i) {
        sage_layer_kernel<<<2048, NTHREADS, 0, stream>>>(
            hi, row_ptr, csr, inv_deg,
            Wl + (size_t)i * 64 * 64, bl + (size_t)i * 64,
            Wr + (size_t)i * 64 * 64, ho, n);
        const float* t = ho; ho = (float*)hi; hi = t;
    }
    // after 3 layers result is in hB (hA->hB->hA->hB), hi points at it
    linear2_kernel<<<2048, NTHREADS, 0, stream>>>(hi, W2, b2, out, n);
}

// Round 2
// 573.221 us; speedup vs baseline: 2.0342x; 2.0342x over previous
//
#include <hip/hip_runtime.h>
#include <hip/hip_bf16.h>

// GraphSAGE forward, split architecture:
//   CSR build -> linear1 (GEMM) -> 3x [agg gather-mean kernel + fused GEMM(norm,relu)] -> linear2 (GEMM)
// All f32 (no fp32 MFMA on CDNA4; vector ALU). GEMM: 128x64 tile, 4x8 micro-tile.

#define NT 256
#define KC 64
#define MT 128
#define SP 68   // As row stride in floats: multiple of 4 (16B-aligned b128) and conflict-analyzed

// ---------------- CSR build ----------------

__global__ void count_kernel(const int* __restrict__ dst, int* __restrict__ cnt, int m) {
    int e = blockIdx.x * blockDim.x + threadIdx.x;
    if (e < m) atomicAdd(&cnt[dst[e]], 1);
}

// single-block exclusive scan of cnt[0..n) -> row_ptr[0..n]
__global__ void scan_kernel(const int* __restrict__ cnt, int* __restrict__ row_ptr, int n) {
    __shared__ int wsum[16];
    __shared__ int s_total;
    __shared__ int s_carry;
    const int tid = threadIdx.x;
    const int lane = tid & 63;
    const int wid = tid >> 6;
    if (tid == 0) s_carry = 0;
    __syncthreads();
    for (int base = 0; base < n; base += 1024) {
        const int i = base + tid;
        int v = (i < n) ? cnt[i] : 0;
        int x = v;
        #pragma unroll
        for (int off = 1; off < 64; off <<= 1) {
            int t = __shfl_up(x, off, 64);
            if (lane >= off) x += t;
        }
        if (lane == 63) wsum[wid] = x;
        __syncthreads();
        if (wid == 0) {
            int wv = (lane < 16) ? wsum[lane] : 0;
            int wx = wv;
            #pragma unroll
            for (int off = 1; off < 16; off <<= 1) {
                int t = __shfl_up(wx, off, 64);
                if (lane >= off) wx += t;
            }
            if (lane == 15) s_total = wx;          // chunk total
            if (lane < 16) wsum[lane] = wx - wv;   // exclusive wave offsets
        }
        __syncthreads();
        const int wave_excl = wsum[wid];
        const int carry = s_carry;
        if (i < n) row_ptr[i] = carry + wave_excl + (x - v);
        __syncthreads();
        if (tid == 0) s_carry = carry + s_total;
        __syncthreads();
    }
    if (tid == 0) row_ptr[n] = s_carry;
}

__global__ void fill_kernel(const int* __restrict__ src, const int* __restrict__ dst,
                            const int* __restrict__ row_ptr, int* __restrict__ cursor,
                            int* __restrict__ csr_src, int m) {
    int e = blockIdx.x * blockDim.x + threadIdx.x;
    if (e < m) {
        int d = dst[e];
        int pos = row_ptr[d] + atomicAdd(&cursor[d], 1);
        csr_src[pos] = src[e];
    }
}

// ---------------- aggregation: agg[node] = mean of hin[src] over in-edges ----------------

__global__ __launch_bounds__(NT) void agg_kernel(const float* __restrict__ hin,
    const int* __restrict__ row_ptr, const int* __restrict__ csr,
    float* __restrict__ agg, int n) {
    const int lane = threadIdx.x & 63;
    const int gw = (blockIdx.x * NT + threadIdx.x) >> 6;
    const int nw = (gridDim.x * NT) >> 6;
    for (int node = gw; node < n; node += nw) {
        const int rs = row_ptr[node];
        const int re = row_ptr[node + 1];
        float acc = 0.0f;
        int e = rs;
        for (; e + 8 <= re; e += 8) {
            const int s0 = csr[e+0], s1 = csr[e+1], s2 = csr[e+2], s3 = csr[e+3];
            const int s4 = csr[e+4], s5 = csr[e+5], s6 = csr[e+6], s7 = csr[e+7];
            const float v0 = hin[(size_t)s0*64 + lane];
            const float v1 = hin[(size_t)s1*64 + lane];
            const float v2 = hin[(size_t)s2*64 + lane];
            const float v3 = hin[(size_t)s3*64 + lane];
            const float v4 = hin[(size_t)s4*64 + lane];
            const float v5 = hin[(size_t)s5*64 + lane];
            const float v6 = hin[(size_t)s6*64 + lane];
            const float v7 = hin[(size_t)s7*64 + lane];
            acc += ((v0+v1)+(v2+v3)) + ((v4+v5)+(v6+v7));
        }
        for (; e < re; ++e) acc += hin[(size_t)csr[e]*64 + lane];
        const float inv = (re > rs) ? (1.0f / (float)(re - rs)) : 0.0f;
        agg[(size_t)node*64 + lane] = acc * inv;
    }
}

// ---------------- GEMM: out[n,64] = A1[n,K1]@W1 (+ A2[n,K2]@W2) + bias; optional L2norm+relu ----------------
// tile: MT=128 rows x 64 cols per block (256 threads); micro-tile 4 rows (strided 32) x 8 cols.

__device__ __forceinline__ float f4c(const float4& v, int kk) {
    return kk == 0 ? v.x : kk == 1 ? v.y : kk == 2 ? v.z : v.w;
}

__global__ __launch_bounds__(NT) void gemm_kernel(
    const float* __restrict__ A1, int ldA1, int K1, const float* __restrict__ W1,
    const float* __restrict__ A2, int ldA2, int K2, const float* __restrict__ W2,
    const float* __restrict__ bias, float* __restrict__ out,
    int n, int do_norm_relu) {
    __shared__ float As[MT * SP];      // 34.0 KB
    __shared__ float Ws[KC * 64];      // 16.0 KB
    const int t  = threadIdx.x;
    const int ct = t & 7;              // col-thread: cols 8*ct .. 8*ct+7
    const int r0 = t >> 3;             // 0..31: rows r0 + 32*i, i=0..3
    const int tile0 = blockIdx.x * MT;

    float acc[4][8];
    {
        const float4 b0 = *(const float4*)&bias[ct*8];
        const float4 b1 = *(const float4*)&bias[ct*8 + 4];
        #pragma unroll
        for (int i = 0; i < 4; ++i) {
            acc[i][0]=b0.x; acc[i][1]=b0.y; acc[i][2]=b0.z; acc[i][3]=b0.w;
            acc[i][4]=b1.x; acc[i][5]=b1.y; acc[i][6]=b1.z; acc[i][7]=b1.w;
        }
    }

    #pragma unroll 1
    for (int s = 0; s < 2; ++s) {
        const float* A   = s ? A2 : A1;
        const float* W   = s ? W2 : W1;
        const int    ldA = s ? ldA2 : ldA1;
        const int    K   = s ? K2  : K1;
        if (!A) continue;
        #pragma unroll 1
        for (int kc = 0; kc < K; kc += KC) {
            __syncthreads();
            // stage A tile: MT rows x KC cols (float4 per row-segment; quarter-wave = one row)
            #pragma unroll
            for (int p = 0; p < 8; ++p) {
                const int i = p * NT + t;
                const int row = i >> 4, cq = i & 15;
                float4 v = make_float4(0.f, 0.f, 0.f, 0.f);
                const int gr = tile0 + row;
                if (gr < n) v = *(const float4*)&A[(size_t)gr * ldA + kc + cq * 4];
                *(float4*)&As[row * SP + cq * 4] = v;
            }
            // stage W chunk: KC x 64
            #pragma unroll
            for (int p = 0; p < 4; ++p) {
                const int i = p * NT + t;
                const int k = i >> 4, cq = i & 15;
                *(float4*)&Ws[k * 64 + cq * 4] = *(const float4*)&W[(size_t)(kc + k) * 64 + cq * 4];
            }
            __syncthreads();
            #pragma unroll 1
            for (int k = 0; k < KC; k += 4) {
                const float4 a0 = *(const float4*)&As[(r0     ) * SP + k];
                const float4 a1 = *(const float4*)&As[(r0 + 32) * SP + k];
                const float4 a2 = *(const float4*)&As[(r0 + 64) * SP + k];
                const float4 a3 = *(const float4*)&As[(r0 + 96) * SP + k];
                #pragma unroll
                for (int kk = 0; kk < 4; ++kk) {
                    const float4 w0 = *(const float4*)&Ws[(k + kk) * 64 + ct * 8];
                    const float4 w1 = *(const float4*)&Ws[(k + kk) * 64 + ct * 8 + 4];
                    const float av0 = f4c(a0, kk), av1 = f4c(a1, kk), av2 = f4c(a2, kk), av3 = f4c(a3, kk);
                    acc[0][0] += av0*w0.x; acc[0][1] += av0*w0.y; acc[0][2] += av0*w0.z; acc[0][3] += av0*w0.w;
                    acc[0][4] += av0*w1.x; acc[0][5] += av0*w1.y; acc[0][6] += av0*w1.z; acc[0][7] += av0*w1.w;
                    acc[1][0] += av1*w0.x; acc[1][1] += av1*w0.y; acc[1][2] += av1*w0.z; acc[1][3] += av1*w0.w;
                    acc[1][4] += av1*w1.x; acc[1][5] += av1*w1.y; acc[1][6] += av1*w1.z; acc[1][7] += av1*w1.w;
                    acc[2][0] += av2*w0.x; acc[2][1] += av2*w0.y; acc[2][2] += av2*w0.z; acc[2][3] += av2*w0.w;
                    acc[2][4] += av2*w1.x; acc[2][5] += av2*w1.y; acc[2][6] += av2*w1.z; acc[2][7] += av2*w1.w;
                    acc[3][0] += av3*w0.x; acc[3][1] += av3*w0.y; acc[3][2] += av3*w0.z; acc[3][3] += av3*w0.w;
                    acc[3][4] += av3*w1.x; acc[3][5] += av3*w1.y; acc[3][6] += av3*w1.z; acc[3][7] += av3*w1.w;
                }
            }
        }
    }

    if (do_norm_relu) {
        #pragma unroll
        for (int i = 0; i < 4; ++i) {
            float ss = 0.0f;
            #pragma unroll
            for (int j = 0; j < 8; ++j) ss += acc[i][j] * acc[i][j];
            ss += __shfl_xor(ss, 1, 64);
            ss += __shfl_xor(ss, 2, 64);
            ss += __shfl_xor(ss, 4, 64);     // full row sum across the 8 col-threads
            const float inv = 1.0f / fmaxf(sqrtf(ss), 1e-12f);
            #pragma unroll
            for (int j = 0; j < 8; ++j) acc[i][j] = fmaxf(acc[i][j] * inv, 0.0f);
        }
    }

    #pragma unroll
    for (int i = 0; i < 4; ++i) {
        const int gr = tile0 + r0 + 32 * i;
        if (gr < n) {
            float4 v0, v1;
            v0.x = acc[i][0]; v0.y = acc[i][1]; v0.z = acc[i][2]; v0.w = acc[i][3];
            v1.x = acc[i][4]; v1.y = acc[i][5]; v1.z = acc[i][6]; v1.w = acc[i][7];
            *(float4*)&out[(size_t)gr * 64 + ct * 8]     = v0;
            *(float4*)&out[(size_t)gr * 64 + ct * 8 + 4] = v1;
        }
    }
}

// ---------------- launch ----------------

extern "C" void kernel_launch(void* const* d_in, const int* in_sizes, int n_in,
                              void* d_out, int out_size, void* d_ws, size_t ws_size,
                              hipStream_t stream) {
    const float* x  = (const float*)d_in[0];
    const int*   ei = (const int*)  d_in[1];
    const float* W1 = (const float*)d_in[2];
    const float* b1 = (const float*)d_in[3];
    const float* Wl = (const float*)d_in[4];
    const float* bl = (const float*)d_in[5];
    const float* Wr = (const float*)d_in[6];
    const float* W2 = (const float*)d_in[7];
    const float* b2 = (const float*)d_in[8];
    float* out = (float*)d_out;

    const int n = in_sizes[0] / 128;   // 100000
    const int m = in_sizes[1] / 2;     // 1250000
    const int* src = ei;
    const int* dst = ei + m;

    char* ws = (char*)d_ws;
    size_t off = 0;
    auto alloc = [&](size_t bytes) -> void* {
        void* p = ws + off;
        off = (off + bytes + 255) & ~(size_t)255;
        return p;
    };
    float* hA      = (float*)alloc((size_t)n * 64 * sizeof(float));
    float* hB      = (float*)alloc((size_t)n * 64 * sizeof(float));
    int*   row_ptr = (int*)  alloc((size_t)(n + 1) * sizeof(int));
    int*   cnt     = (int*)  alloc((size_t)n * sizeof(int));
    int*   cursor  = (int*)  alloc((size_t)n * sizeof(int));
    int*   csr     = (int*)  alloc((size_t)m * sizeof(int));

    hipMemsetAsync(cnt, 0, (size_t)n * sizeof(int), stream);
    hipMemsetAsync(cursor, 0, (size_t)n * sizeof(int), stream);

    const int eb = (m + NT - 1) / NT;
    count_kernel<<<eb, NT, 0, stream>>>(dst, cnt, m);
    scan_kernel<<<1, 1024, 0, stream>>>(cnt, row_ptr, n);
    fill_kernel<<<eb, NT, 0, stream>>>(src, dst, row_ptr, cursor, csr, m);

    const int gtiles = (n + MT - 1) / MT;   // 782

    // h0 = x @ W1 + b1   -> hA
    gemm_kernel<<<gtiles, NT, 0, stream>>>(x, 128, 128, W1,
                                           nullptr, 0, 0, nullptr,
                                           b1, hA, n, 0);

    // ping-pong: hi holds current h, ho receives next h (agg staged in ho first)
    const float* hi = hA;
    float* ho = hB;
    for (int i = 0; i < 3; ++i) {
        agg_kernel<<<2048, NT, 0, stream>>>(hi, row_ptr, csr, ho, n);
        gemm_kernel<<<gtiles, NT, 0, stream>>>(ho, 64, 64, Wl + (size_t)i * 64 * 64,
                                               hi, 64, 64, Wr + (size_t)i * 64 * 64,
                                               bl + (size_t)i * 64, ho, n, 1);
        const float* tp = ho; ho = (float*)hi; hi = tp;
    }
    // after 3 layers: hi = hB (hA -> hB -> hA -> hB)
    gemm_kernel<<<gtiles, NT, 0, stream>>>(hi, 64, 64, W2,
                                           nullptr, 0, 0, nullptr,
                                           b2, out, n, 0);
}

// Round 3
// 401.356 us; speedup vs baseline: 2.9053x; 1.4282x over previous
//
#include <hip/hip_runtime.h>
#include <hip/hip_bf16.h>

// GraphSAGE forward:
//   CSR build (count+rank -> hierarchical scan -> fill, no cursor atomics)
//   linear1 (GEMM) -> 3x [agg gather-mean (bf16 reads) + GEMM(norm,relu)] -> linear2
// Arithmetic all f32 (no fp32 MFMA on CDNA4); h stored bf16 to halve gather traffic.

#define NT 256
#define MT 128
#define KC 32
#define SP 36   // As row stride (floats): 16B-aligned, bank-conflict-free (36%32=4)

__device__ __forceinline__ float bfbits2f(unsigned short b) {
    return __uint_as_float(((unsigned)b) << 16);
}

// ---------------- CSR build ----------------

__global__ void count_kernel(const int* __restrict__ dst, int* __restrict__ cnt,
                             int* __restrict__ rank, int m) {
    int e = blockIdx.x * blockDim.x + threadIdx.x;
    if (e < m) rank[e] = atomicAdd(&cnt[dst[e]], 1);
}

// per-1024-chunk sums
__global__ void reduce_chunk_kernel(const int* __restrict__ cnt, int* __restrict__ bsum, int n) {
    __shared__ int ws[4];
    const int t = threadIdx.x, lane = t & 63, wid = t >> 6;
    const int base = blockIdx.x * 1024;
    int s = 0;
    #pragma unroll
    for (int p = 0; p < 4; ++p) {
        const int idx = base + p * 256 + t;
        s += (idx < n) ? cnt[idx] : 0;
    }
    #pragma unroll
    for (int off = 32; off > 0; off >>= 1) s += __shfl_xor(s, off, 64);
    if (lane == 0) ws[wid] = s;
    __syncthreads();
    if (t == 0) bsum[blockIdx.x] = ws[0] + ws[1] + ws[2] + ws[3];
}

// 1 block, 128 threads: exclusive scan of nb (<=128) chunk sums; writes row_ptr[n]=total
__global__ void scan_bsums_kernel(const int* __restrict__ bsum, int* __restrict__ bexcl,
                                  int* __restrict__ row_ptr, int n, int nb) {
    __shared__ int w0;
    const int t = threadIdx.x, lane = t & 63, wid = t >> 6;
    const int v = (t < nb) ? bsum[t] : 0;
    int x = v;
    #pragma unroll
    for (int off = 1; off < 64; off <<= 1) {
        const int tt = __shfl_up(x, off, 64);
        if (lane >= off) x += tt;
    }
    if (wid == 0 && lane == 63) w0 = x;
    __syncthreads();
    const int incl = x + (wid ? w0 : 0);
    if (t < nb) bexcl[t] = incl - v;
    if (t == nb - 1) row_ptr[n] = incl;
}

// per-chunk exclusive scan + chunk offset -> row_ptr
__global__ void scan_apply_kernel(const int* __restrict__ cnt, const int* __restrict__ bexcl,
                                  int* __restrict__ row_ptr, int n) {
    __shared__ int wsum[4];
    const int t = threadIdx.x, lane = t & 63, wid = t >> 6;
    const int base = blockIdx.x * 1024 + t * 4;
    int4 v = make_int4(0, 0, 0, 0);
    if (base + 3 < n) v = *(const int4*)&cnt[base];
    else {
        if (base < n)     v.x = cnt[base];
        if (base + 1 < n) v.y = cnt[base + 1];
        if (base + 2 < n) v.z = cnt[base + 2];
    }
    const int tsum = v.x + v.y + v.z + v.w;
    int x = tsum;
    #pragma unroll
    for (int off = 1; off < 64; off <<= 1) {
        const int tt = __shfl_up(x, off, 64);
        if (lane >= off) x += tt;
    }
    if (lane == 63) wsum[wid] = x;
    __syncthreads();
    int woff = 0;
    for (int w = 0; w < wid; ++w) woff += wsum[w];
    int e = bexcl[blockIdx.x] + woff + (x - tsum);
    int4 o;
    o.x = e; o.y = e + v.x; o.z = o.y + v.y; o.w = o.z + v.z;
    if (base + 3 < n) *(int4*)&row_ptr[base] = o;
    else {
        if (base < n)     row_ptr[base]     = o.x;
        if (base + 1 < n) row_ptr[base + 1] = o.y;
        if (base + 2 < n) row_ptr[base + 2] = o.z;
    }
}

__global__ void fill_kernel(const int* __restrict__ src, const int* __restrict__ dst,
                            const int* __restrict__ row_ptr, const int* __restrict__ rank,
                            int* __restrict__ csr, int m) {
    int e = blockIdx.x * blockDim.x + threadIdx.x;
    if (e < m) csr[row_ptr[dst[e]] + rank[e]] = src[e];
}

// ---------------- aggregation: agg[node] = mean over in-edges of h_bf16[src] ----------------

__global__ __launch_bounds__(NT) void agg_kernel(const __hip_bfloat16* __restrict__ hin,
    const int* __restrict__ row_ptr, const int* __restrict__ csr,
    float* __restrict__ agg, int n) {
    const unsigned short* h = (const unsigned short*)hin;
    const int lane = threadIdx.x & 63;
    const int gw = (blockIdx.x * NT + threadIdx.x) >> 6;
    const int nw = (gridDim.x * NT) >> 6;
    for (int node = gw; node < n; node += nw) {
        const int rs = row_ptr[node];
        const int re = row_ptr[node + 1];
        float acc = 0.0f;
        int e = rs;
        for (; e + 8 <= re; e += 8) {
            const int s0 = csr[e+0], s1 = csr[e+1], s2 = csr[e+2], s3 = csr[e+3];
            const int s4 = csr[e+4], s5 = csr[e+5], s6 = csr[e+6], s7 = csr[e+7];
            const float v0 = bfbits2f(h[(size_t)s0*64 + lane]);
            const float v1 = bfbits2f(h[(size_t)s1*64 + lane]);
            const float v2 = bfbits2f(h[(size_t)s2*64 + lane]);
            const float v3 = bfbits2f(h[(size_t)s3*64 + lane]);
            const float v4 = bfbits2f(h[(size_t)s4*64 + lane]);
            const float v5 = bfbits2f(h[(size_t)s5*64 + lane]);
            const float v6 = bfbits2f(h[(size_t)s6*64 + lane]);
            const float v7 = bfbits2f(h[(size_t)s7*64 + lane]);
            acc += ((v0+v1)+(v2+v3)) + ((v4+v5)+(v6+v7));
        }
        for (; e < re; ++e) acc += bfbits2f(h[(size_t)csr[e]*64 + lane]);
        const float inv = (re > rs) ? (1.0f / (float)(re - rs)) : 0.0f;
        agg[(size_t)node*64 + lane] = acc * inv;
    }
}

// ---------------- GEMM: out = A1_f32@W1 (+ A2_bf16@W2) + bias; optional L2norm+relu ----------------
// 128x64 tile / block (256 thr); micro-tile 4 rows (stride 32) x 8 cols.

__device__ __forceinline__ float f4c(const float4& v, int kk) {
    return kk == 0 ? v.x : kk == 1 ? v.y : kk == 2 ? v.z : v.w;
}

__device__ __forceinline__ void compute_chunk(const float* __restrict__ As,
                                              const float* __restrict__ Ws,
                                              float acc[4][8], int r0, int ct) {
    #pragma unroll
    for (int k = 0; k < KC; k += 4) {
        const float4 a0 = *(const float4*)&As[(r0      ) * SP + k];
        const float4 a1 = *(const float4*)&As[(r0 +  32) * SP + k];
        const float4 a2 = *(const float4*)&As[(r0 +  64) * SP + k];
        const float4 a3 = *(const float4*)&As[(r0 +  96) * SP + k];
        #pragma unroll
        for (int kk = 0; kk < 4; ++kk) {
            const float4 w0 = *(const float4*)&Ws[(k + kk) * 64 + ct * 8];
            const float4 w1 = *(const float4*)&Ws[(k + kk) * 64 + ct * 8 + 4];
            const float av0 = f4c(a0, kk), av1 = f4c(a1, kk), av2 = f4c(a2, kk), av3 = f4c(a3, kk);
            acc[0][0] += av0*w0.x; acc[0][1] += av0*w0.y; acc[0][2] += av0*w0.z; acc[0][3] += av0*w0.w;
            acc[0][4] += av0*w1.x; acc[0][5] += av0*w1.y; acc[0][6] += av0*w1.z; acc[0][7] += av0*w1.w;
            acc[1][0] += av1*w0.x; acc[1][1] += av1*w0.y; acc[1][2] += av1*w0.z; acc[1][3] += av1*w0.w;
            acc[1][4] += av1*w1.x; acc[1][5] += av1*w1.y; acc[1][6] += av1*w1.z; acc[1][7] += av1*w1.w;
            acc[2][0] += av2*w0.x; acc[2][1] += av2*w0.y; acc[2][2] += av2*w0.z; acc[2][3] += av2*w0.w;
            acc[2][4] += av2*w1.x; acc[2][5] += av2*w1.y; acc[2][6] += av2*w1.z; acc[2][7] += av2*w1.w;
            acc[3][0] += av3*w0.x; acc[3][1] += av3*w0.y; acc[3][2] += av3*w0.z; acc[3][3] += av3*w0.w;
            acc[3][4] += av3*w1.x; acc[3][5] += av3*w1.y; acc[3][6] += av3*w1.z; acc[3][7] += av3*w1.w;
        }
    }
}

__global__ __launch_bounds__(NT, 4) void gemm_kernel(
    const float* __restrict__ A1, int ldA1, int K1, const float* __restrict__ W1,
    const __hip_bfloat16* __restrict__ A2, int K2, const float* __restrict__ W2,
    const float* __restrict__ bias, float* __restrict__ outF,
    __hip_bfloat16* __restrict__ outB, int n, int do_norm_relu) {
    __shared__ float As[MT * SP];      // 18 KB
    __shared__ float Ws[KC * 64];      // 8 KB
    const int t  = threadIdx.x;
    const int ct = t & 7;
    const int r0 = t >> 3;
    const int tile0 = blockIdx.x * MT;

    float acc[4][8];
    {
        const float4 b0 = *(const float4*)&bias[ct*8];
        const float4 b1 = *(const float4*)&bias[ct*8 + 4];
        #pragma unroll
        for (int i = 0; i < 4; ++i) {
            acc[i][0]=b0.x; acc[i][1]=b0.y; acc[i][2]=b0.z; acc[i][3]=b0.w;
            acc[i][4]=b1.x; acc[i][5]=b1.y; acc[i][6]=b1.z; acc[i][7]=b1.w;
        }
    }

    if (A1) {
        #pragma unroll 1
        for (int kc = 0; kc < K1; kc += KC) {
            __syncthreads();
            #pragma unroll
            for (int p = 0; p < 4; ++p) {                 // A tile: 128 rows x 32 f32
                const int i = p * NT + t;
                const int row = i >> 3, cq = i & 7;
                float4 v = make_float4(0.f, 0.f, 0.f, 0.f);
                const int gr = tile0 + row;
                if (gr < n) v = *(const float4*)&A1[(size_t)gr * ldA1 + kc + cq * 4];
                *(float4*)&As[row * SP + cq * 4] = v;
            }
            #pragma unroll
            for (int p = 0; p < 2; ++p) {                 // W chunk: 32 x 64
                const int i = p * NT + t;
                const int k = i >> 4, cq = i & 15;
                *(float4*)&Ws[k * 64 + cq * 4] = *(const float4*)&W1[(size_t)(kc + k) * 64 + cq * 4];
            }
            __syncthreads();
            compute_chunk(As, Ws, acc, r0, ct);
        }
    }
    if (A2) {
        const unsigned short* A2u = (const unsigned short*)A2;
        #pragma unroll 1
        for (int kc = 0; kc < K2; kc += KC) {
            __syncthreads();
            #pragma unroll
            for (int p = 0; p < 4; ++p) {                 // A tile: 128 rows x 32 bf16 -> f32
                const int i = p * NT + t;
                const int row = i >> 3, cq = i & 7;
                float4 v = make_float4(0.f, 0.f, 0.f, 0.f);
                const int gr = tile0 + row;
                if (gr < n) {
                    const ushort4 u = *(const ushort4*)&A2u[(size_t)gr * 64 + kc + cq * 4];
                    v.x = bfbits2f(u.x); v.y = bfbits2f(u.y);
                    v.z = bfbits2f(u.z); v.w = bfbits2f(u.w);
                }
                *(float4*)&As[row * SP + cq * 4] = v;
            }
            #pragma unroll
            for (int p = 0; p < 2; ++p) {
                const int i = p * NT + t;
                const int k = i >> 4, cq = i & 15;
                *(float4*)&Ws[k * 64 + cq * 4] = *(const float4*)&W2[(size_t)(kc + k) * 64 + cq * 4];
            }
            __syncthreads();
            compute_chunk(As, Ws, acc, r0, ct);
        }
    }

    if (do_norm_relu) {
        #pragma unroll
        for (int i = 0; i < 4; ++i) {
            float ss = 0.0f;
            #pragma unroll
            for (int j = 0; j < 8; ++j) ss += acc[i][j] * acc[i][j];
            ss += __shfl_xor(ss, 1, 64);
            ss += __shfl_xor(ss, 2, 64);
            ss += __shfl_xor(ss, 4, 64);
            const float inv = 1.0f / fmaxf(sqrtf(ss), 1e-12f);
            #pragma unroll
            for (int j = 0; j < 8; ++j) acc[i][j] = fmaxf(acc[i][j] * inv, 0.0f);
        }
    }

    #pragma unroll
    for (int i = 0; i < 4; ++i) {
        const int gr = tile0 + r0 + 32 * i;
        if (gr >= n) continue;
        if (outF) {
            float4 v0, v1;
            v0.x = acc[i][0]; v0.y = acc[i][1]; v0.z = acc[i][2]; v0.w = acc[i][3];
            v1.x = acc[i][4]; v1.y = acc[i][5]; v1.z = acc[i][6]; v1.w = acc[i][7];
            *(float4*)&outF[(size_t)gr * 64 + ct * 8]     = v0;
            *(float4*)&outF[(size_t)gr * 64 + ct * 8 + 4] = v1;
        }
        if (outB) {
            union { __hip_bfloat16 h[8]; uint4 u; } pk;
            #pragma unroll
            for (int j = 0; j < 8; ++j) pk.h[j] = __float2bfloat16(acc[i][j]);
            *(uint4*)&outB[(size_t)gr * 64 + ct * 8] = pk.u;
        }
    }
}

// ---------------- launch ----------------

extern "C" void kernel_launch(void* const* d_in, const int* in_sizes, int n_in,
                              void* d_out, int out_size, void* d_ws, size_t ws_size,
                              hipStream_t stream) {
    const float* x  = (const float*)d_in[0];
    const int*   ei = (const int*)  d_in[1];
    const float* W1 = (const float*)d_in[2];
    const float* b1 = (const float*)d_in[3];
    const float* Wl = (const float*)d_in[4];
    const float* bl = (const float*)d_in[5];
    const float* Wr = (const float*)d_in[6];
    const float* W2 = (const float*)d_in[7];
    const float* b2 = (const float*)d_in[8];
    float* out = (float*)d_out;

    const int n = in_sizes[0] / 128;   // 100000
    const int m = in_sizes[1] / 2;     // 1250000
    const int* src = ei;
    const int* dst = ei + m;

    char* ws = (char*)d_ws;
    size_t off = 0;
    auto alloc = [&](size_t bytes) -> void* {
        void* p = ws + off;
        off = (off + bytes + 255) & ~(size_t)255;
        return p;
    };
    float*          aggF    = (float*)alloc((size_t)n * 64 * sizeof(float));
    __hip_bfloat16* hbf     = (__hip_bfloat16*)alloc((size_t)n * 64 * sizeof(__hip_bfloat16));
    int*            row_ptr = (int*)alloc((size_t)(n + 1) * sizeof(int));
    int*            cnt     = (int*)alloc((size_t)n * sizeof(int));
    int*            bsum    = (int*)alloc(512);
    int*            bexcl   = (int*)alloc(512);
    int*            rank    = (int*)alloc((size_t)m * sizeof(int));
    int*            csr     = (int*)alloc((size_t)m * sizeof(int));

    hipMemsetAsync(cnt, 0, (size_t)n * sizeof(int), stream);

    const int eb = (m + NT - 1) / NT;
    const int NB = (n + 1023) / 1024;           // 98 (<=128 required by scan_bsums)
    count_kernel<<<eb, NT, 0, stream>>>(dst, cnt, rank, m);
    reduce_chunk_kernel<<<NB, NT, 0, stream>>>(cnt, bsum, n);
    scan_bsums_kernel<<<1, 128, 0, stream>>>(bsum, bexcl, row_ptr, n, NB);
    scan_apply_kernel<<<NB, NT, 0, stream>>>(cnt, bexcl, row_ptr, n);
    fill_kernel<<<eb, NT, 0, stream>>>(src, dst, row_ptr, rank, csr, m);

    const int gtiles = (n + MT - 1) / MT;       // 782

    // h0 = x @ W1 + b1  -> hbf (bf16)
    gemm_kernel<<<gtiles, NT, 0, stream>>>(x, 128, 128, W1,
                                           nullptr, 0, nullptr,
                                           b1, nullptr, hbf, n, 0);

    for (int i = 0; i < 3; ++i) {
        agg_kernel<<<2048, NT, 0, stream>>>(hbf, row_ptr, csr, aggF, n);
        // h <- relu(l2norm(agg@Wl + bl + h@Wr)), in place on hbf (each block touches only its own rows)
        gemm_kernel<<<gtiles, NT, 0, stream>>>(aggF, 64, 64, Wl + (size_t)i * 64 * 64,
                                               hbf, 64, Wr + (size_t)i * 64 * 64,
                                               bl + (size_t)i * 64, nullptr, hbf, n, 1);
    }
    // out = h @ W2 + b2 (f32)
    gemm_kernel<<<gtiles, NT, 0, stream>>>(nullptr, 0, 0, nullptr,
                                           hbf, 64, W2,
                                           b2, out, nullptr, n, 0);
}

// Round 4
// 273.798 us; speedup vs baseline: 4.2588x; 1.4659x over previous
//
#include <hip/hip_runtime.h>
#include <hip/hip_bf16.h>

// GraphSAGE forward:
//   CSR build -> [wconv] -> linear1 (MFMA) -> 3x [agg gather-mean bf16 + MFMA GEMM(norm,relu)] -> linear2
// h/agg stored bf16; GEMMs via mfma_f32_16x16x32_bf16 (f32 accumulate); no LDS, no barriers in GEMM.

#define NT 256

typedef __attribute__((ext_vector_type(8))) short bf16x8;
typedef __attribute__((ext_vector_type(4))) float f32x4;

__device__ __forceinline__ float bfbits2f(unsigned short b) {
    return __uint_as_float(((unsigned)b) << 16);
}
__device__ __forceinline__ unsigned short f2bfbits(float v) {
    __hip_bfloat16 b = __float2bfloat16(v);
    return *reinterpret_cast<unsigned short*>(&b);
}

// ---------------- CSR build ----------------

__global__ void count_kernel(const int* __restrict__ dst, int* __restrict__ cnt,
                             int* __restrict__ rank, int m) {
    int e = blockIdx.x * blockDim.x + threadIdx.x;
    if (e < m) rank[e] = atomicAdd(&cnt[dst[e]], 1);
}

__global__ void reduce_chunk_kernel(const int* __restrict__ cnt, int* __restrict__ bsum, int n) {
    __shared__ int ws[4];
    const int t = threadIdx.x, lane = t & 63, wid = t >> 6;
    const int base = blockIdx.x * 1024;
    int s = 0;
    #pragma unroll
    for (int p = 0; p < 4; ++p) {
        const int idx = base + p * 256 + t;
        s += (idx < n) ? cnt[idx] : 0;
    }
    #pragma unroll
    for (int off = 32; off > 0; off >>= 1) s += __shfl_xor(s, off, 64);
    if (lane == 0) ws[wid] = s;
    __syncthreads();
    if (t == 0) bsum[blockIdx.x] = ws[0] + ws[1] + ws[2] + ws[3];
}

__global__ void scan_bsums_kernel(const int* __restrict__ bsum, int* __restrict__ bexcl,
                                  int* __restrict__ row_ptr, int n, int nb) {
    __shared__ int w0;
    const int t = threadIdx.x, lane = t & 63, wid = t >> 6;
    const int v = (t < nb) ? bsum[t] : 0;
    int x = v;
    #pragma unroll
    for (int off = 1; off < 64; off <<= 1) {
        const int tt = __shfl_up(x, off, 64);
        if (lane >= off) x += tt;
    }
    if (wid == 0 && lane == 63) w0 = x;
    __syncthreads();
    const int incl = x + (wid ? w0 : 0);
    if (t < nb) bexcl[t] = incl - v;
    if (t == nb - 1) row_ptr[n] = incl;
}

__global__ void scan_apply_kernel(const int* __restrict__ cnt, const int* __restrict__ bexcl,
                                  int* __restrict__ row_ptr, int n) {
    __shared__ int wsum[4];
    const int t = threadIdx.x, lane = t & 63, wid = t >> 6;
    const int base = blockIdx.x * 1024 + t * 4;
    int4 v = make_int4(0, 0, 0, 0);
    if (base + 3 < n) v = *(const int4*)&cnt[base];
    else {
        if (base < n)     v.x = cnt[base];
        if (base + 1 < n) v.y = cnt[base + 1];
        if (base + 2 < n) v.z = cnt[base + 2];
    }
    const int tsum = v.x + v.y + v.z + v.w;
    int x = tsum;
    #pragma unroll
    for (int off = 1; off < 64; off <<= 1) {
        const int tt = __shfl_up(x, off, 64);
        if (lane >= off) x += tt;
    }
    if (lane == 63) wsum[wid] = x;
    __syncthreads();
    int woff = 0;
    for (int w = 0; w < wid; ++w) woff += wsum[w];
    int e = bexcl[blockIdx.x] + woff + (x - tsum);
    int4 o;
    o.x = e; o.y = e + v.x; o.z = o.y + v.y; o.w = o.z + v.z;
    if (base + 3 < n) *(int4*)&row_ptr[base] = o;
    else {
        if (base < n)     row_ptr[base]     = o.x;
        if (base + 1 < n) row_ptr[base + 1] = o.y;
        if (base + 2 < n) row_ptr[base + 2] = o.z;
    }
}

__global__ void fill_kernel(const int* __restrict__ src, const int* __restrict__ dst,
                            const int* __restrict__ row_ptr, const int* __restrict__ rank,
                            int* __restrict__ csr, int m) {
    int e = blockIdx.x * blockDim.x + threadIdx.x;
    if (e < m) csr[row_ptr[dst[e]] + rank[e]] = src[e];
}

// ---------------- weight convert+transpose: Wt[col][k] bf16 ----------------
// layout in out: W1t[64][128] @0 ; per layer m: Wlt[64][64] @8192+m*8192, Wrt @+4096 ; W2t @32768

__global__ void wconv_kernel(const float* __restrict__ W1, const float* __restrict__ Wl,
                             const float* __restrict__ Wr, const float* __restrict__ W2,
                             unsigned short* __restrict__ out) {
    int i = blockIdx.x * blockDim.x + threadIdx.x;
    if (i >= 36864) return;
    float v;
    if (i < 8192) {
        const int col = i >> 7, k = i & 127;
        v = W1[k * 64 + col];
    } else if (i < 32768) {
        const int j = i - 8192;
        const int mm = j >> 13, r = j & 8191;
        const int isR = (r >> 12) & 1, q = r & 4095;
        const int col = q >> 6, k = q & 63;
        v = (isR ? Wr : Wl)[mm * 4096 + k * 64 + col];
    } else {
        const int q = i - 32768;
        const int col = q >> 6, k = q & 63;
        v = W2[k * 64 + col];
    }
    out[i] = f2bfbits(v);
}

// ---------------- aggregation: aggB[node] = bf16(mean over in-edges of h[src]) ----------------
// lane split: g=lane>>4 (edge slot), c=lane&15 (4 cols each). 4 edges per wave-load.

__global__ __launch_bounds__(NT) void agg_kernel(const unsigned short* __restrict__ h,
    const int* __restrict__ row_ptr, const int* __restrict__ csr,
    unsigned short* __restrict__ aggB, int n) {
    const int t = threadIdx.x;
    const int lane = t & 63;
    const int g = lane >> 4;
    const int c = lane & 15;
    const int gw = (blockIdx.x * NT + t) >> 6;
    const int nw = (gridDim.x * NT) >> 6;
    for (int node = gw; node < n; node += nw) {
        const int rs = row_ptr[node];
        const int re = row_ptr[node + 1];
        float a0 = 0.f, a1 = 0.f, a2 = 0.f, a3 = 0.f;
        int e = rs;
        for (; e + 8 <= re; e += 8) {
            const int s0 = csr[e + g];
            const int s1 = csr[e + 4 + g];
            const ushort4 v0 = *(const ushort4*)&h[(size_t)s0 * 64 + c * 4];
            const ushort4 v1 = *(const ushort4*)&h[(size_t)s1 * 64 + c * 4];
            a0 += bfbits2f(v0.x) + bfbits2f(v1.x);
            a1 += bfbits2f(v0.y) + bfbits2f(v1.y);
            a2 += bfbits2f(v0.z) + bfbits2f(v1.z);
            a3 += bfbits2f(v0.w) + bfbits2f(v1.w);
        }
        for (; e + 4 <= re; e += 4) {
            const int s0 = csr[e + g];
            const ushort4 v0 = *(const ushort4*)&h[(size_t)s0 * 64 + c * 4];
            a0 += bfbits2f(v0.x);
            a1 += bfbits2f(v0.y);
            a2 += bfbits2f(v0.z);
            a3 += bfbits2f(v0.w);
        }
        const int r = re - e;
        if (g < r) {
            const int s0 = csr[e + g];
            const ushort4 v0 = *(const ushort4*)&h[(size_t)s0 * 64 + c * 4];
            a0 += bfbits2f(v0.x);
            a1 += bfbits2f(v0.y);
            a2 += bfbits2f(v0.z);
            a3 += bfbits2f(v0.w);
        }
        // reduce across the 4 edge-slots (lane bits 4,5)
        a0 += __shfl_xor(a0, 16, 64); a0 += __shfl_xor(a0, 32, 64);
        a1 += __shfl_xor(a1, 16, 64); a1 += __shfl_xor(a1, 32, 64);
        a2 += __shfl_xor(a2, 16, 64); a2 += __shfl_xor(a2, 32, 64);
        a3 += __shfl_xor(a3, 16, 64); a3 += __shfl_xor(a3, 32, 64);
        if (g == 0) {
            const float inv = (re > rs) ? (1.0f / (float)(re - rs)) : 0.0f;
            ushort4 o;
            o.x = f2bfbits(a0 * inv);
            o.y = f2bfbits(a1 * inv);
            o.z = f2bfbits(a2 * inv);
            o.w = f2bfbits(a3 * inv);
            *(ushort4*)&aggB[(size_t)node * 64 + c * 4] = o;
        }
    }
}

// ---------------- MFMA GEMM: C[n,64] = A1@W1 [+ A2@W2] + bias; optional L2norm+relu ----------------
// block = 4 waves, wave = 32 rows x 64 cols (2 row-tiles x 4 col-tiles of 16x16x32 mfma).
// A-frag: lane = A[row0+(l&15)][kc+(l>>4)*8 ..+8] (global dwordx4).
// B-frag: lane = Wt[col0+(l&15)][kc+(l>>4)*8 ..+8] (global, Wt = W^T bf16).
// C/D: col = lane&15, row = (lane>>4)*4 + reg.

template<int A1F32>
__global__ __launch_bounds__(NT) void gemm_mfma(
    const float* __restrict__ A1f, const unsigned short* __restrict__ A1b,
    int ldA1, int K1, const unsigned short* __restrict__ W1t,
    const unsigned short* __restrict__ A2b, const unsigned short* __restrict__ W2t,
    const float* __restrict__ bias, float* __restrict__ outF,
    unsigned short* __restrict__ outB, int n, int do_norm) {
    const int t = threadIdx.x;
    const int lane = t & 63;
    const int w = t >> 6;
    const int r16 = lane & 15;
    const int g = lane >> 4;
    const int row0 = blockIdx.x * 128 + w * 32;

    f32x4 acc[2][4];
    #pragma unroll
    for (int i = 0; i < 2; ++i)
        #pragma unroll
        for (int j = 0; j < 4; ++j) {
            acc[i][j][0] = 0.f; acc[i][j][1] = 0.f; acc[i][j][2] = 0.f; acc[i][j][3] = 0.f;
        }

    int ra[2];
    #pragma unroll
    for (int rt = 0; rt < 2; ++rt) {
        int r = row0 + rt * 16 + r16;
        ra[rt] = (r < n) ? r : (n - 1);
    }

    // ---- source 1 ----
    #pragma unroll 1
    for (int kc = 0; kc < K1; kc += 32) {
        bf16x8 af[2];
        #pragma unroll
        for (int rt = 0; rt < 2; ++rt) {
            if (A1F32) {
                const float* p = &A1f[(size_t)ra[rt] * ldA1 + kc + g * 8];
                const float4 f0 = *(const float4*)p;
                const float4 f1 = *(const float4*)(p + 4);
                bf16x8 a;
                a[0] = (short)f2bfbits(f0.x); a[1] = (short)f2bfbits(f0.y);
                a[2] = (short)f2bfbits(f0.z); a[3] = (short)f2bfbits(f0.w);
                a[4] = (short)f2bfbits(f1.x); a[5] = (short)f2bfbits(f1.y);
                a[6] = (short)f2bfbits(f1.z); a[7] = (short)f2bfbits(f1.w);
                af[rt] = a;
            } else {
                af[rt] = *(const bf16x8*)&A1b[(size_t)ra[rt] * ldA1 + kc + g * 8];
            }
        }
        #pragma unroll
        for (int ct = 0; ct < 4; ++ct) {
            const bf16x8 bw = *(const bf16x8*)&W1t[(size_t)(ct * 16 + r16) * K1 + kc + g * 8];
            acc[0][ct] = __builtin_amdgcn_mfma_f32_16x16x32_bf16(af[0], bw, acc[0][ct], 0, 0, 0);
            acc[1][ct] = __builtin_amdgcn_mfma_f32_16x16x32_bf16(af[1], bw, acc[1][ct], 0, 0, 0);
        }
    }
    // ---- source 2 (bf16, ld=64, K=64) ----
    if (A2b) {
        #pragma unroll 1
        for (int kc = 0; kc < 64; kc += 32) {
            bf16x8 af[2];
            #pragma unroll
            for (int rt = 0; rt < 2; ++rt)
                af[rt] = *(const bf16x8*)&A2b[(size_t)ra[rt] * 64 + kc + g * 8];
            #pragma unroll
            for (int ct = 0; ct < 4; ++ct) {
                const bf16x8 bw = *(const bf16x8*)&W2t[(size_t)(ct * 16 + r16) * 64 + kc + g * 8];
                acc[0][ct] = __builtin_amdgcn_mfma_f32_16x16x32_bf16(af[0], bw, acc[0][ct], 0, 0, 0);
                acc[1][ct] = __builtin_amdgcn_mfma_f32_16x16x32_bf16(af[1], bw, acc[1][ct], 0, 0, 0);
            }
        }
    }

    // ---- epilogue ----
    float bcol[4];
    #pragma unroll
    for (int ct = 0; ct < 4; ++ct) bcol[ct] = bias[ct * 16 + r16];

    #pragma unroll
    for (int rt = 0; rt < 2; ++rt) {
        #pragma unroll
        for (int ct = 0; ct < 4; ++ct)
            #pragma unroll
            for (int reg = 0; reg < 4; ++reg) acc[rt][ct][reg] += bcol[ct];

        if (do_norm) {
            #pragma unroll
            for (int reg = 0; reg < 4; ++reg) {
                float ss = 0.f;
                #pragma unroll
                for (int ct = 0; ct < 4; ++ct) ss += acc[rt][ct][reg] * acc[rt][ct][reg];
                ss += __shfl_xor(ss, 1, 64);
                ss += __shfl_xor(ss, 2, 64);
                ss += __shfl_xor(ss, 4, 64);
                ss += __shfl_xor(ss, 8, 64);
                const float inv = 1.0f / fmaxf(sqrtf(ss), 1e-12f);
                #pragma unroll
                for (int ct = 0; ct < 4; ++ct)
                    acc[rt][ct][reg] = fmaxf(acc[rt][ct][reg] * inv, 0.0f);
            }
        }

        const int rbase = row0 + rt * 16 + g * 4;
        #pragma unroll
        for (int reg = 0; reg < 4; ++reg) {
            const int rr = rbase + reg;
            if (rr < n) {
                if (outB) {
                    #pragma unroll
                    for (int ct = 0; ct < 4; ++ct)
                        outB[(size_t)rr * 64 + ct * 16 + r16] = f2bfbits(acc[rt][ct][reg]);
                } else {
                    #pragma unroll
                    for (int ct = 0; ct < 4; ++ct)
                        outF[(size_t)rr * 64 + ct * 16 + r16] = acc[rt][ct][reg];
                }
            }
        }
    }
}

// ---------------- launch ----------------

extern "C" void kernel_launch(void* const* d_in, const int* in_sizes, int n_in,
                              void* d_out, int out_size, void* d_ws, size_t ws_size,
                              hipStream_t stream) {
    const float* x  = (const float*)d_in[0];
    const int*   ei = (const int*)  d_in[1];
    const float* W1 = (const float*)d_in[2];
    const float* b1 = (const float*)d_in[3];
    const float* Wl = (const float*)d_in[4];
    const float* bl = (const float*)d_in[5];
    const float* Wr = (const float*)d_in[6];
    const float* W2 = (const float*)d_in[7];
    const float* b2 = (const float*)d_in[8];
    float* out = (float*)d_out;

    const int n = in_sizes[0] / 128;   // 100000
    const int m = in_sizes[1] / 2;     // 1250000
    const int* src = ei;
    const int* dst = ei + m;

    char* ws = (char*)d_ws;
    size_t off = 0;
    auto alloc = [&](size_t bytes) -> void* {
        void* p = ws + off;
        off = (off + bytes + 255) & ~(size_t)255;
        return p;
    };
    unsigned short* aggB    = (unsigned short*)alloc((size_t)n * 64 * 2);
    unsigned short* hbf     = (unsigned short*)alloc((size_t)n * 64 * 2);
    int*            row_ptr = (int*)alloc((size_t)(n + 1) * sizeof(int));
    int*            cnt     = (int*)alloc((size_t)n * sizeof(int));
    int*            bsum    = (int*)alloc(512);
    int*            bexcl   = (int*)alloc(512);
    int*            rank    = (int*)alloc((size_t)m * sizeof(int));
    int*            csr     = (int*)alloc((size_t)m * sizeof(int));
    unsigned short* wt      = (unsigned short*)alloc(36864 * 2);

    const unsigned short* W1t = wt;
    const unsigned short* W2t = wt + 32768;

    hipMemsetAsync(cnt, 0, (size_t)n * sizeof(int), stream);

    const int eb = (m + NT - 1) / NT;
    const int NB = (n + 1023) / 1024;           // 98 (<=128 required by scan_bsums)
    count_kernel<<<eb, NT, 0, stream>>>(dst, cnt, rank, m);
    reduce_chunk_kernel<<<NB, NT, 0, stream>>>(cnt, bsum, n);
    scan_bsums_kernel<<<1, 128, 0, stream>>>(bsum, bexcl, row_ptr, n, NB);
    scan_apply_kernel<<<NB, NT, 0, stream>>>(cnt, bexcl, row_ptr, n);
    fill_kernel<<<eb, NT, 0, stream>>>(src, dst, row_ptr, rank, csr, m);
    wconv_kernel<<<144, NT, 0, stream>>>(W1, Wl, Wr, W2, wt);

    const int gtiles = (n + 127) / 128;         // 782

    // h0 = x @ W1 + b1 -> hbf (bf16)
    gemm_mfma<1><<<gtiles, NT, 0, stream>>>(x, nullptr, 128, 128, W1t,
                                            nullptr, nullptr, b1, nullptr, hbf, n, 0);

    for (int i = 0; i < 3; ++i) {
        agg_kernel<<<2048, NT, 0, stream>>>(hbf, row_ptr, csr, aggB, n);
        const unsigned short* Wlt = wt + 8192 + (size_t)i * 8192;
        const unsigned short* Wrt = Wlt + 4096;
        // h <- relu(l2norm(agg@Wl + bl + h@Wr)), in place on hbf (each wave reads only its own rows)
        gemm_mfma<0><<<gtiles, NT, 0, stream>>>(nullptr, aggB, 64, 64, Wlt,
                                                hbf, Wrt, bl + (size_t)i * 64,
                                                nullptr, hbf, n, 1);
    }
    // out = h @ W2 + b2 (f32)
    gemm_mfma<0><<<gtiles, NT, 0, stream>>>(nullptr, hbf, 64, 64, W2t,
                                            nullptr, nullptr, b2, out, nullptr, n, 0);
}